// Round 3
// baseline (247.991 us; speedup 1.0000x reference)
//
#include <hip/hip_runtime.h>
#include <math.h>

#define B    64
#define NV   40000
#define P    100
#define KG   128
#define NJ   24
#define TVJ  16           // vertices per jpart sub-tile
#define TVS  32           // vertices per skin block
#define NSK  31           // skeleton joints: 1 zero + 23 + 7
#define NSUB (KG / TVJ)   // 8 sub-tiles per joint
#define NBLK (NV / TVS)   // 1250 skin blocks
#define NSPIN 160         // skin blocks that stay for the skel tail
#define NTASK (30 * B)    // 1920 skel tasks (= NSPIN * 12)

typedef __attribute__((ext_vector_type(8))) short bf16x8;
typedef __attribute__((ext_vector_type(4))) float f32x4;

__device__ __forceinline__ unsigned short rne_bf16(float f) {
  unsigned u = __float_as_uint(f);
  u = (u + 0x7FFFu + ((u >> 16) & 1u)) >> 16;
  return (unsigned short)u;
}

// ---------------------------------------------------------------------------
// Kernel 1: jpart (184 blocks, body identical to the 158us baseline) + chain
// folded into the LAST block via ticket (release: threadfence+atomicAdd;
// acquire: threadfence after observing ticket 183). Chain: Jl reduced in
// parallel by 256 threads into LDS, then 64 lanes walk one batch each
// through the 24-joint serial kinematic chain in registers.
// ---------------------------------------------------------------------------
__global__ __launch_bounds__(256)
void k_jc(const float* __restrict__ beta,
          const float* __restrict__ sd,
          const float* __restrict__ vt,
          const int*   __restrict__ joint_idx,
          const float* __restrict__ pose,
          const float* __restrict__ trans,
          float*       __restrict__ pmn,
          float*       __restrict__ pmx,
          unsigned short* __restrict__ G1A,
          unsigned short* __restrict__ beta_bf,
          int*         __restrict__ cnt) {
  const int j = blockIdx.x;   // 0..22
  const int s = blockIdx.y;   // 0..7
  const int t = threadIdx.x;  // 0..255
  const int lane = t & 63, wv = t >> 6;
  const int l15 = lane & 15, qd = lane >> 4;

  // union: jpart carve (31KB) / chain carve (55.3KB)
  __shared__ __align__(16) unsigned char smem[55296];
  unsigned short* beta_s = (unsigned short*)smem;            // [64][136]
  unsigned short* sdT_s  = (unsigned short*)(smem + 17408);  // [48][136]
  float*          vt_s   = (float*)(smem + 30464);           // [48]
  int*            idx_s  = (int*)(smem + 30656);             // [16]
  float*          pos_s  = (float*)smem;                     // alias [64][68]
  __shared__ int s_old;

  if (t < TVJ) idx_s[t] = joint_idx[j * KG + s * TVJ + t];
  __syncthreads();

  for (int e = t; e < 64 * 36; e += 256) {
    const int m = e / 36, pp = P + e % 36;
    beta_s[m * 136 + pp] = 0;
  }
  for (int e = t; e < 64 * P; e += 256) {
    const int m = e / P, p = e % P;
    beta_s[m * 136 + p] = rne_bf16(beta[e]);
  }
  for (int task = t; task < 768; task += 256) {
    const int n = task % 48, kg = task / 48;
    const size_t colbase = (size_t)idx_s[n / 3] * 3 + (n % 3);
    unsigned pk[4];
#pragma unroll
    for (int h = 0; h < 4; ++h) {
      const int k0 = kg * 8 + 2 * h;
      float f0 = 0.0f, f1 = 0.0f;
      if (k0 < P)     f0 = sd[(size_t)k0 * (3 * NV) + colbase];
      if (k0 + 1 < P) f1 = sd[(size_t)(k0 + 1) * (3 * NV) + colbase];
      pk[h] = (unsigned)rne_bf16(f0) | ((unsigned)rne_bf16(f1) << 16);
    }
    *(uint4*)&sdT_s[n * 136 + kg * 8] = make_uint4(pk[0], pk[1], pk[2], pk[3]);
  }
  if (t < 48) vt_s[t] = vt[(size_t)idx_s[t / 3] * 3 + (t % 3)];
  __syncthreads();

  // D(64x48) = beta(64x128) @ sdT(128x48); wave = M-tile of 16 batches
  bf16x8 af[4];
#pragma unroll
  for (int ks = 0; ks < 4; ++ks)
    af[ks] = *(const bf16x8*)&beta_s[(wv * 16 + l15) * 136 + ks * 32 + qd * 8];
  f32x4 acc[3];
#pragma unroll
  for (int nt = 0; nt < 3; ++nt) acc[nt] = (f32x4){0.f, 0.f, 0.f, 0.f};
#pragma unroll
  for (int ks = 0; ks < 4; ++ks) {
#pragma unroll
    for (int nt = 0; nt < 3; ++nt) {
      const bf16x8 bf = *(const bf16x8*)&sdT_s[(nt * 16 + l15) * 136 + ks * 32 + qd * 8];
      acc[nt] = __builtin_amdgcn_mfma_f32_16x16x32_bf16(af[ks], bf, acc[nt], 0, 0, 0);
    }
  }
  float vtv[3];
#pragma unroll
  for (int nt = 0; nt < 3; ++nt) vtv[nt] = vt_s[nt * 16 + l15];
  __syncthreads();   // fragment reads done before aliased pos writes

#pragma unroll
  for (int nt = 0; nt < 3; ++nt) {
    const int n = nt * 16 + l15;
    const int v = n / 3, c = n - 3 * v;
#pragma unroll
    for (int r = 0; r < 4; ++r) {
      const int m = wv * 16 + qd * 4 + r;   // batch
      pos_s[m * 68 + v * 4 + c] = acc[nt][r] + vtv[nt];
    }
  }
  __syncthreads();

  if (t < 192) {
    const int b = t / 3, c = t % 3;
    float lo = 1e30f, hi = -1e30f;
#pragma unroll
    for (int v = 0; v < TVJ; ++v) {
      const float val = pos_s[b * 68 + v * 4 + c];
      lo = fminf(lo, val); hi = fmaxf(hi, val);
    }
    pmn[((j * NSUB + s) * B + b) * 3 + c] = lo;
    pmx[((j * NSUB + s) * B + b) * 3 + c] = hi;
  }

  // ------------------- ticket: last block runs the chain -------------------
  __syncthreads();                    // drains all vmem (stores in L2)
  if (t == 0) { __threadfence(); s_old = atomicAdd(cnt, 1); }  // release
  __syncthreads();
  if (s_old != 23 * NSUB - 1) return;
  __threadfence();                    // acquire: invalidate caches

  // chain carve
  float* Jl_c = (float*)smem;             // [(j*3+c)*64 + b]  18432 B
  float* Gl   = (float*)(smem + 18432);   // [b][12][12]       36864 B

  // zero G1A (poisoned workspace!), convert beta_bf, reduce Jl — parallel
  {
    const uint4 z4 = make_uint4(0, 0, 0, 0);
    for (int e = t; e < 4096; e += 256) ((uint4*)G1A)[e] = z4;
  }
  for (int e = t; e < 64 * 136; e += 256) {
    const int b = e / 136, k = e - b * 136;
    beta_bf[e] = (k < P) ? rne_bf16(beta[b * P + k]) : (unsigned short)0;
  }
  for (int e = t; e < 192; e += 256) Jl_c[e] = 0.0f;   // joint 0 = origin
  for (int e = t; e < 23 * 192; e += 256) {
    const int jj = e / 192, rem = e - jj * 192;        // rem = b*3+c
    const int b = rem / 3, c = rem - b * 3;
    float lo = 1e30f, hi = -1e30f;
#pragma unroll
    for (int s2 = 0; s2 < NSUB; ++s2) {
      lo = fminf(lo, pmn[(jj * NSUB + s2) * 192 + rem]);
      hi = fmaxf(hi, pmx[(jj * NSUB + s2) * 192 + rem]);
    }
    Jl_c[((jj + 1) * 3 + c) * 64 + b] = 0.5f * (lo + hi);
  }
  __syncthreads();

  if (t < 64) {
    const int b = t;
    float px = pose[b * 72 + 0], py = pose[b * 72 + 1], pz = pose[b * 72 + 2];
    float G_[12];
#pragma unroll 1
    for (int i = 0; i < NJ; ++i) {
      float nx = 0.f, ny = 0.f, nz = 0.f;
      if (i < NJ - 1) {
        nx = pose[b * 72 + (i + 1) * 3 + 0];
        ny = pose[b * 72 + (i + 1) * 3 + 1];
        nz = pose[b * 72 + (i + 1) * 3 + 2];
      }
      const float th = fmaxf(sqrtf(px * px + py * py + pz * pz), 1e-6f);
      const float xh = px / th, yh = py / th, zh = pz / th;
      const float cc = cosf(th), ss = sinf(th), oo = 1.0f - cc;
      float R9[9];
      R9[0] = cc + oo * xh * xh;      R9[1] = oo * xh * yh - ss * zh; R9[2] = oo * xh * zh + ss * yh;
      R9[3] = oo * xh * yh + ss * zh; R9[4] = cc + oo * yh * yh;      R9[5] = oo * yh * zh - ss * xh;
      R9[6] = oo * xh * zh - ss * yh; R9[7] = oo * yh * zh + ss * xh; R9[8] = cc + oo * zh * zh;

      const float ji0 = Jl_c[(i * 3 + 0) * 64 + b];
      const float ji1 = Jl_c[(i * 3 + 1) * 64 + b];
      const float ji2 = Jl_c[(i * 3 + 2) * 64 + b];

      if (i == 0) {
#pragma unroll
        for (int r = 0; r < 3; ++r) {
          G_[r * 4 + 0] = R9[r * 3 + 0];
          G_[r * 4 + 1] = R9[r * 3 + 1];
          G_[r * 4 + 2] = R9[r * 3 + 2];
          G_[r * 4 + 3] = 0.0f;   // Jl[0] = origin
        }
      } else {
        const int p = (i - 1) >> 1;
        const float d0 = ji0 - Jl_c[(p * 3 + 0) * 64 + b];
        const float d1 = ji1 - Jl_c[(p * 3 + 1) * 64 + b];
        const float d2 = ji2 - Jl_c[(p * 3 + 2) * 64 + b];
        float Gn[12];
#pragma unroll
        for (int r = 0; r < 3; ++r) {
          const float g0 = Gl[(b * 12 + p) * 12 + r * 4 + 0];
          const float g1 = Gl[(b * 12 + p) * 12 + r * 4 + 1];
          const float g2 = Gl[(b * 12 + p) * 12 + r * 4 + 2];
          const float g3 = Gl[(b * 12 + p) * 12 + r * 4 + 3];
          Gn[r * 4 + 0] = g0 * R9[0] + g1 * R9[3] + g2 * R9[6];
          Gn[r * 4 + 1] = g0 * R9[1] + g1 * R9[4] + g2 * R9[7];
          Gn[r * 4 + 2] = g0 * R9[2] + g1 * R9[5] + g2 * R9[8];
          Gn[r * 4 + 3] = g0 * d0 + g1 * d1 + g2 * d2 + g3;
        }
#pragma unroll
        for (int e = 0; e < 12; ++e) G_[e] = Gn[e];
      }
      if (i < 12) {
#pragma unroll
        for (int e = 0; e < 12; ++e) Gl[(b * 12 + i) * 12 + e] = G_[e];
      }
#pragma unroll
      for (int r = 0; r < 3; ++r) {
        const float tc = G_[r * 4 + 0] * ji0 + G_[r * 4 + 1] * ji1 + G_[r * 4 + 2] * ji2;
        G1A[b * 512 + (r * 4 + 0) * 32 + i] = rne_bf16(G_[r * 4 + 0]);
        G1A[b * 512 + (r * 4 + 1) * 32 + i] = rne_bf16(G_[r * 4 + 1]);
        G1A[b * 512 + (r * 4 + 2) * 32 + i] = rne_bf16(G_[r * 4 + 2]);
        G1A[b * 512 + (r * 4 + 3) * 32 + i] = rne_bf16(G_[r * 4 + 3] - tc);
      }
      px = nx; py = ny; pz = nz;
    }
  } else if (t >= 192) {
    // trans slots: A[(r*4+3)][k==24] = trans[b][r]
#pragma unroll
    for (int k = 0; k < 3; ++k) {
      const int e = (t - 192) * 3 + k;   // 0..191
      const int b = e / 3, r = e - b * 3;
      G1A[b * 512 + (r * 4 + 3) * 32 + 24] = rne_bf16(trans[b * 3 + r]);
    }
  }
}

// ---------------------------------------------------------------------------
// Kernel 2: skin (body identical to the R1 version that passed) + skel
// folded into the LAST NSPIN blocks: after finishing its tile, each block
// takes a ticket; the last 160 spin (s_sleep) until all 1250 are done,
// then each reduces 12 of the 1920 skeleton tasks (2 per round, half-block
// each). <=160 spinners < 768 resident slots => forward progress.
// ---------------------------------------------------------------------------
__global__ __launch_bounds__(256)
void k_ss(const float* __restrict__ sd,
          const float* __restrict__ vt,
          const float* __restrict__ w,
          const unsigned short* __restrict__ beta_bf,
          const unsigned short* __restrict__ G1A,
          const int*   __restrict__ joint_idx,
          const int*   __restrict__ add_idx,
          float*       __restrict__ out,
          float*       __restrict__ skel,
          int*         __restrict__ cnt) {
  const int n0v  = blockIdx.x * TVS;
  const int col0 = n0v * 3;            // 96 columns per block
  const int t  = threadIdx.x;
  const int lane = t & 63, wv = t >> 6;
  const int l15 = lane & 15, q = lane >> 4;

  __shared__ __align__(16) unsigned char smem[46464];
  unsigned short* beta_s = (unsigned short*)smem;             // [64][136]  17408 B
  unsigned short* sdT_s  = (unsigned short*)(smem + 17408);   // [96][136]  26112 B
  unsigned short* wT_s   = (unsigned short*)(smem + 43520);   // [32][40]    2560 B
  float*          vt_s   = (float*)(smem + 46080);            // [96]         384 B
  float*          vhf    = (float*)smem;                      // alias [64][128] f32
  __shared__ int s_old;

  for (int e = t; e < 1088; e += 256)
    ((uint4*)beta_s)[e] = ((const uint4*)beta_bf)[e];
  for (int task = t; task < 1536; task += 256) {
    const int n = task % 96, kg = task / 96;
    unsigned pk[4];
#pragma unroll
    for (int h = 0; h < 4; ++h) {
      const int k0 = kg * 8 + 2 * h;
      float f0 = 0.0f, f1 = 0.0f;
      if (k0 < P)     f0 = sd[(size_t)k0 * (3 * NV) + col0 + n];
      if (k0 + 1 < P) f1 = sd[(size_t)(k0 + 1) * (3 * NV) + col0 + n];
      pk[h] = (unsigned)rne_bf16(f0) | ((unsigned)rne_bf16(f1) << 16);
    }
    *(uint4*)&sdT_s[n * 136 + kg * 8] = make_uint4(pk[0], pk[1], pk[2], pk[3]);
  }
  for (int e = t; e < 1024; e += 256) {
    const int n = e >> 5, k = e & 31;
    float val = (k < NJ) ? w[(n0v + n) * NJ + k] : (k == NJ ? 1.0f : 0.0f);
    wT_s[n * 40 + k] = rne_bf16(val);
  }
  if (t < 96) vt_s[t] = vt[col0 + t];
  __syncthreads();

  // phase 1: D(64x96) = beta(64x128) @ sdT(128x96)
  bf16x8 af[4];
#pragma unroll
  for (int ks = 0; ks < 4; ++ks)
    af[ks] = *(const bf16x8*)&beta_s[(wv * 16 + l15) * 136 + ks * 32 + q * 8];
  f32x4 acc[6];
#pragma unroll
  for (int nt = 0; nt < 6; ++nt) acc[nt] = (f32x4){0.f, 0.f, 0.f, 0.f};
#pragma unroll
  for (int ks = 0; ks < 4; ++ks) {
#pragma unroll
    for (int nt = 0; nt < 6; ++nt) {
      const bf16x8 bf = *(const bf16x8*)&sdT_s[(nt * 16 + l15) * 136 + ks * 32 + q * 8];
      acc[nt] = __builtin_amdgcn_mfma_f32_16x16x32_bf16(af[ks], bf, acc[nt], 0, 0, 0);
    }
  }
  __syncthreads();   // fragment reads done before aliased writes

#pragma unroll
  for (int nt = 0; nt < 6; ++nt) {
    const int n = nt * 16 + l15;
    const int v = n / 3, c = n - 3 * v;
    const float vtn = vt_s[n];
#pragma unroll
    for (int r = 0; r < 4; ++r) {
      const int m = wv * 16 + q * 4 + r;   // batch
      vhf[m * 128 + v * 4 + c] = acc[nt][r] + vtn;
    }
  }
  __syncthreads();

  // phase 2: T = G1A(b) @ w^T via MFMA; dot with vh; store direct.
  const bf16x8 wf0 = *(const bf16x8*)&wT_s[l15 * 40 + q * 8];
  const bf16x8 wf1 = *(const bf16x8*)&wT_s[(16 + l15) * 40 + q * 8];
  const f32x4 zero = (f32x4){0.f, 0.f, 0.f, 0.f};
#pragma unroll 4
  for (int bi = 0; bi < 16; ++bi) {
    const int b = wv * 16 + bi;
    const bf16x8 gf = *(const bf16x8*)&G1A[(size_t)b * 512 + l15 * 32 + q * 8];
    const f32x4 d0 = __builtin_amdgcn_mfma_f32_16x16x32_bf16(gf, wf0, zero, 0, 0, 0);
    const f32x4 d1 = __builtin_amdgcn_mfma_f32_16x16x32_bf16(gf, wf1, zero, 0, 0, 0);
    const float4 vh0 = *(const float4*)&vhf[b * 128 + l15 * 4];
    const float4 vh1 = *(const float4*)&vhf[b * 128 + 64 + l15 * 4];
    if (q < 3) {
      out[(size_t)b * (NV * 3) + col0 + l15 * 3 + q] =
          d0[0] * vh0.x + d0[1] * vh0.y + d0[2] * vh0.z + d0[3];
      out[(size_t)b * (NV * 3) + col0 + 48 + l15 * 3 + q] =
          d1[0] * vh1.x + d1[1] * vh1.y + d1[2] * vh1.z + d1[3];
    }
  }

  // ----------------------- skel tail (last NSPIN blocks) -------------------
  __syncthreads();                    // drain all out-stores
  if (t == 0) { __threadfence(); s_old = atomicAdd(cnt, 1); }  // release
  __syncthreads();
  const int old = s_old;
  if (old < NBLK - NSPIN) return;
  if (t == 0) {
    while (__hip_atomic_load(cnt, __ATOMIC_RELAXED, __HIP_MEMORY_SCOPE_AGENT) < NBLK)
      __builtin_amdgcn_s_sleep(2);
  }
  __syncthreads();
  __threadfence();                    // acquire
  const int rank = old - (NBLK - NSPIN);   // 0..NSPIN-1

  float* s_red = (float*)smem;        // [half][wave][6] = 24 floats
  const int h  = t >> 7;              // half-block
  const int th = t & 127;
  const int wvh = th >> 6, ln = th & 63;
#pragma unroll 1
  for (int rd = 0; rd < 6; ++rd) {
    const int task = rank * 12 + rd * 2 + h;   // < 1920
    const int jj = task >> 6;          // 0..29
    const int b  = task & 63;
    const int idx = (jj < 23) ? joint_idx[jj * KG + th] : add_idx[(jj - 23) * KG + th];
    const float* pp = out + (size_t)b * NV * 3 + (size_t)idx * 3;
    float mn[3], mx[3];
#pragma unroll
    for (int c = 0; c < 3; ++c) { mn[c] = pp[c]; mx[c] = pp[c]; }
#pragma unroll
    for (int off = 32; off > 0; off >>= 1) {
#pragma unroll
      for (int c = 0; c < 3; ++c) {
        mn[c] = fminf(mn[c], __shfl_down(mn[c], off));
        mx[c] = fmaxf(mx[c], __shfl_down(mx[c], off));
      }
    }
    if (ln == 0) {
#pragma unroll
      for (int c = 0; c < 3; ++c) {
        s_red[(h * 2 + wvh) * 6 + c]     = mn[c];
        s_red[(h * 2 + wvh) * 6 + 3 + c] = mx[c];
      }
    }
    __syncthreads();
    if (th == 0) {
#pragma unroll
      for (int c = 0; c < 3; ++c) {
        const float lo = fminf(s_red[(h * 2) * 6 + c],     s_red[(h * 2 + 1) * 6 + c]);
        const float hi = fmaxf(s_red[(h * 2) * 6 + 3 + c], s_red[(h * 2 + 1) * 6 + 3 + c]);
        skel[(b * NSK + 1 + jj) * 3 + c] = 0.5f * (lo + hi);
        if (jj == 0) skel[(b * NSK + 0) * 3 + c] = 0.0f;
      }
    }
    __syncthreads();
  }
}

// ---------------------------------------------------------------------------
extern "C" void kernel_launch(void* const* d_in, const int* in_sizes, int n_in,
                              void* d_out, int out_size, void* d_ws, size_t ws_size,
                              hipStream_t stream) {
  const float* beta     = (const float*)d_in[0];
  const float* pose     = (const float*)d_in[1];
  const float* trans    = (const float*)d_in[2];
  const float* sd       = (const float*)d_in[3];
  const float* vt       = (const float*)d_in[4];
  const float* w        = (const float*)d_in[5];
  // d_in[6] = reorder_index (identity arange -> unused)
  // d_in[7] = parent (implicit (i-1)/2 binary tree -> folded into k_jc)
  const int* joint_idx  = (const int*)d_in[8];
  const int* add_idx    = (const int*)d_in[9];

  float* out  = (float*)d_out;
  float* skel = out + (size_t)B * NV * 3;
  unsigned short* G1A     = (unsigned short*)d_ws;            // 64*512 us
  unsigned short* beta_bf = G1A + B * 512;                    // 64*136 us
  float* pmn = (float*)(beta_bf + B * 136);                   // 23*8*64*3 f
  float* pmx = pmn + 23 * NSUB * B * 3;
  int*   cnt = (int*)(pmx + 23 * NSUB * B * 3);               // [0]=jc [1]=ss

  hipMemsetAsync(cnt, 0, 16, stream);
  k_jc<<<dim3(23, NSUB), 256, 0, stream>>>(beta, sd, vt, joint_idx, pose, trans,
                                           pmn, pmx, G1A, beta_bf, cnt + 0);
  k_ss<<<NBLK, 256, 0, stream>>>(sd, vt, w, beta_bf, G1A, joint_idx, add_idx,
                                 out, skel, cnt + 1);
}

// Round 4
// 196.730 us; speedup vs baseline: 1.2606x; 1.2606x over previous
//
#include <hip/hip_runtime.h>
#include <math.h>

#define B    64
#define NV   40000
#define P    100
#define KG   128
#define NJ   24
#define TVJ  16           // vertices per jpart sub-tile
#define TVS  16           // vertices per skin block
#define NSK  31           // skeleton joints: 1 zero + 23 + 7
#define NSUB (KG / TVJ)   // 8 sub-tiles per joint

typedef __attribute__((ext_vector_type(8))) short bf16x8;
typedef __attribute__((ext_vector_type(4))) float f32x4;

__device__ __forceinline__ unsigned short rne_bf16(float f) {
  unsigned u = __float_as_uint(f);
  u = (u + 0x7FFFu + ((u >> 16) & 1u)) >> 16;
  return (unsigned short)u;
}

// ---------------------------------------------------------------------------
// Kernel 1: jpart (184 blocks) + chain folded into the LAST block via ticket.
// Verified passing in R3 (absmax 0.03125); body unchanged.
// ---------------------------------------------------------------------------
__global__ __launch_bounds__(256)
void k_jc(const float* __restrict__ beta,
          const float* __restrict__ sd,
          const float* __restrict__ vt,
          const int*   __restrict__ joint_idx,
          const float* __restrict__ pose,
          const float* __restrict__ trans,
          float*       __restrict__ pmn,
          float*       __restrict__ pmx,
          unsigned short* __restrict__ G1A,
          unsigned short* __restrict__ beta_bf,
          int*         __restrict__ cnt) {
  const int j = blockIdx.x;   // 0..22
  const int s = blockIdx.y;   // 0..7
  const int t = threadIdx.x;  // 0..255
  const int lane = t & 63, wv = t >> 6;
  const int l15 = lane & 15, qd = lane >> 4;

  __shared__ __align__(16) unsigned char smem[55296];
  unsigned short* beta_s = (unsigned short*)smem;            // [64][136]
  unsigned short* sdT_s  = (unsigned short*)(smem + 17408);  // [48][136]
  float*          vt_s   = (float*)(smem + 30464);           // [48]
  int*            idx_s  = (int*)(smem + 30656);             // [16]
  float*          pos_s  = (float*)smem;                     // alias [64][68]
  __shared__ int s_old;

  if (t < TVJ) idx_s[t] = joint_idx[j * KG + s * TVJ + t];
  __syncthreads();

  for (int e = t; e < 64 * 36; e += 256) {
    const int m = e / 36, pp = P + e % 36;
    beta_s[m * 136 + pp] = 0;
  }
  for (int e = t; e < 64 * P; e += 256) {
    const int m = e / P, p = e % P;
    beta_s[m * 136 + p] = rne_bf16(beta[e]);
  }
  for (int task = t; task < 768; task += 256) {
    const int n = task % 48, kg = task / 48;
    const size_t colbase = (size_t)idx_s[n / 3] * 3 + (n % 3);
    unsigned pk[4];
#pragma unroll
    for (int h = 0; h < 4; ++h) {
      const int k0 = kg * 8 + 2 * h;
      float f0 = 0.0f, f1 = 0.0f;
      if (k0 < P)     f0 = sd[(size_t)k0 * (3 * NV) + colbase];
      if (k0 + 1 < P) f1 = sd[(size_t)(k0 + 1) * (3 * NV) + colbase];
      pk[h] = (unsigned)rne_bf16(f0) | ((unsigned)rne_bf16(f1) << 16);
    }
    *(uint4*)&sdT_s[n * 136 + kg * 8] = make_uint4(pk[0], pk[1], pk[2], pk[3]);
  }
  if (t < 48) vt_s[t] = vt[(size_t)idx_s[t / 3] * 3 + (t % 3)];
  __syncthreads();

  bf16x8 af[4];
#pragma unroll
  for (int ks = 0; ks < 4; ++ks)
    af[ks] = *(const bf16x8*)&beta_s[(wv * 16 + l15) * 136 + ks * 32 + qd * 8];
  f32x4 acc[3];
#pragma unroll
  for (int nt = 0; nt < 3; ++nt) acc[nt] = (f32x4){0.f, 0.f, 0.f, 0.f};
#pragma unroll
  for (int ks = 0; ks < 4; ++ks) {
#pragma unroll
    for (int nt = 0; nt < 3; ++nt) {
      const bf16x8 bf = *(const bf16x8*)&sdT_s[(nt * 16 + l15) * 136 + ks * 32 + qd * 8];
      acc[nt] = __builtin_amdgcn_mfma_f32_16x16x32_bf16(af[ks], bf, acc[nt], 0, 0, 0);
    }
  }
  float vtv[3];
#pragma unroll
  for (int nt = 0; nt < 3; ++nt) vtv[nt] = vt_s[nt * 16 + l15];
  __syncthreads();

#pragma unroll
  for (int nt = 0; nt < 3; ++nt) {
    const int n = nt * 16 + l15;
    const int v = n / 3, c = n - 3 * v;
#pragma unroll
    for (int r = 0; r < 4; ++r) {
      const int m = wv * 16 + qd * 4 + r;
      pos_s[m * 68 + v * 4 + c] = acc[nt][r] + vtv[nt];
    }
  }
  __syncthreads();

  if (t < 192) {
    const int b = t / 3, c = t % 3;
    float lo = 1e30f, hi = -1e30f;
#pragma unroll
    for (int v = 0; v < TVJ; ++v) {
      const float val = pos_s[b * 68 + v * 4 + c];
      lo = fminf(lo, val); hi = fmaxf(hi, val);
    }
    pmn[((j * NSUB + s) * B + b) * 3 + c] = lo;
    pmx[((j * NSUB + s) * B + b) * 3 + c] = hi;
  }

  // ------------------- ticket: last block runs the chain -------------------
  __syncthreads();
  if (t == 0) { __threadfence(); s_old = atomicAdd(cnt, 1); }  // release
  __syncthreads();
  if (s_old != 23 * NSUB - 1) return;
  __threadfence();                    // acquire

  float* Jl_c = (float*)smem;             // [(j*3+c)*64 + b]  18432 B
  float* Gl   = (float*)(smem + 18432);   // [b][12][12]       36864 B

  {
    const uint4 z4 = make_uint4(0, 0, 0, 0);
    for (int e = t; e < 4096; e += 256) ((uint4*)G1A)[e] = z4;
  }
  for (int e = t; e < 64 * 136; e += 256) {
    const int b = e / 136, k = e - b * 136;
    beta_bf[e] = (k < P) ? rne_bf16(beta[b * P + k]) : (unsigned short)0;
  }
  for (int e = t; e < 192; e += 256) Jl_c[e] = 0.0f;
  for (int e = t; e < 23 * 192; e += 256) {
    const int jj = e / 192, rem = e - jj * 192;
    const int b = rem / 3, c = rem - b * 3;
    float lo = 1e30f, hi = -1e30f;
#pragma unroll
    for (int s2 = 0; s2 < NSUB; ++s2) {
      lo = fminf(lo, pmn[(jj * NSUB + s2) * 192 + rem]);
      hi = fmaxf(hi, pmx[(jj * NSUB + s2) * 192 + rem]);
    }
    Jl_c[((jj + 1) * 3 + c) * 64 + b] = 0.5f * (lo + hi);
  }
  __syncthreads();

  if (t < 64) {
    const int b = t;
    float px = pose[b * 72 + 0], py = pose[b * 72 + 1], pz = pose[b * 72 + 2];
    float G_[12];
#pragma unroll 1
    for (int i = 0; i < NJ; ++i) {
      float nx = 0.f, ny = 0.f, nz = 0.f;
      if (i < NJ - 1) {
        nx = pose[b * 72 + (i + 1) * 3 + 0];
        ny = pose[b * 72 + (i + 1) * 3 + 1];
        nz = pose[b * 72 + (i + 1) * 3 + 2];
      }
      const float th = fmaxf(sqrtf(px * px + py * py + pz * pz), 1e-6f);
      const float xh = px / th, yh = py / th, zh = pz / th;
      const float cc = cosf(th), ss = sinf(th), oo = 1.0f - cc;
      float R9[9];
      R9[0] = cc + oo * xh * xh;      R9[1] = oo * xh * yh - ss * zh; R9[2] = oo * xh * zh + ss * yh;
      R9[3] = oo * xh * yh + ss * zh; R9[4] = cc + oo * yh * yh;      R9[5] = oo * yh * zh - ss * xh;
      R9[6] = oo * xh * zh - ss * yh; R9[7] = oo * yh * zh + ss * xh; R9[8] = cc + oo * zh * zh;

      const float ji0 = Jl_c[(i * 3 + 0) * 64 + b];
      const float ji1 = Jl_c[(i * 3 + 1) * 64 + b];
      const float ji2 = Jl_c[(i * 3 + 2) * 64 + b];

      if (i == 0) {
#pragma unroll
        for (int r = 0; r < 3; ++r) {
          G_[r * 4 + 0] = R9[r * 3 + 0];
          G_[r * 4 + 1] = R9[r * 3 + 1];
          G_[r * 4 + 2] = R9[r * 3 + 2];
          G_[r * 4 + 3] = 0.0f;
        }
      } else {
        const int p = (i - 1) >> 1;
        const float d0 = ji0 - Jl_c[(p * 3 + 0) * 64 + b];
        const float d1 = ji1 - Jl_c[(p * 3 + 1) * 64 + b];
        const float d2 = ji2 - Jl_c[(p * 3 + 2) * 64 + b];
        float Gn[12];
#pragma unroll
        for (int r = 0; r < 3; ++r) {
          const float g0 = Gl[(b * 12 + p) * 12 + r * 4 + 0];
          const float g1 = Gl[(b * 12 + p) * 12 + r * 4 + 1];
          const float g2 = Gl[(b * 12 + p) * 12 + r * 4 + 2];
          const float g3 = Gl[(b * 12 + p) * 12 + r * 4 + 3];
          Gn[r * 4 + 0] = g0 * R9[0] + g1 * R9[3] + g2 * R9[6];
          Gn[r * 4 + 1] = g0 * R9[1] + g1 * R9[4] + g2 * R9[7];
          Gn[r * 4 + 2] = g0 * R9[2] + g1 * R9[5] + g2 * R9[8];
          Gn[r * 4 + 3] = g0 * d0 + g1 * d1 + g2 * d2 + g3;
        }
#pragma unroll
        for (int e = 0; e < 12; ++e) G_[e] = Gn[e];
      }
      if (i < 12) {
#pragma unroll
        for (int e = 0; e < 12; ++e) Gl[(b * 12 + i) * 12 + e] = G_[e];
      }
#pragma unroll
      for (int r = 0; r < 3; ++r) {
        const float tc = G_[r * 4 + 0] * ji0 + G_[r * 4 + 1] * ji1 + G_[r * 4 + 2] * ji2;
        G1A[b * 512 + (r * 4 + 0) * 32 + i] = rne_bf16(G_[r * 4 + 0]);
        G1A[b * 512 + (r * 4 + 1) * 32 + i] = rne_bf16(G_[r * 4 + 1]);
        G1A[b * 512 + (r * 4 + 2) * 32 + i] = rne_bf16(G_[r * 4 + 2]);
        G1A[b * 512 + (r * 4 + 3) * 32 + i] = rne_bf16(G_[r * 4 + 3] - tc);
      }
      px = nx; py = ny; pz = nz;
    }
  } else if (t >= 192) {
#pragma unroll
    for (int k = 0; k < 3; ++k) {
      const int e = (t - 192) * 3 + k;
      const int b = e / 3, r = e - b * 3;
      G1A[b * 512 + (r * 4 + 3) * 32 + 24] = rne_bf16(trans[b * 3 + r]);
    }
  }
}

// ---------------------------------------------------------------------------
// Kernel 2: skin, restructured staging. sd is loaded as float4 into an f32
// LDS tile [100][48] (1200 vector loads/block, no conversion in the staging
// path — was 4800 scalar loads + 4800 rne packs). MFMA B-fragments are
// built on-the-fly from the f32 tile (8 strided ds_read_b32 + cvt per
// fragment; 4-way bank alias on these 96 reads/lane only — negligible).
// LDS 38.1KB -> 4 blocks/CU (16 waves/CU) vs 3 at TVS=32. Direct stores.
// ---------------------------------------------------------------------------
__global__ __launch_bounds__(256)
void k_skin(const float* __restrict__ sd,
            const float* __restrict__ vt,
            const float* __restrict__ w,
            const unsigned short* __restrict__ beta_bf,
            const unsigned short* __restrict__ G1A,
            float*       __restrict__ out) {
  const int n0v  = blockIdx.x * TVS;
  const int col0 = n0v * 3;            // 48 columns per block
  const int t  = threadIdx.x;
  const int lane = t & 63, wv = t >> 6;
  const int l15 = lane & 15, q = lane >> 4;

  __shared__ __align__(16) unsigned char smem[38080];
  unsigned short* beta_s = (unsigned short*)smem;             // [64][136] 17408 B
  float*          sdf    = (float*)(smem + 17408);            // [100][48] 19200 B
  unsigned short* wT_s   = (unsigned short*)(smem + 36608);   // [16][40]   1280 B
  float*          vt_s   = (float*)(smem + 37888);            // [48]        192 B
  float*          vhf    = (float*)smem;                      // alias [64][68] f32

  for (int e = t; e < 1088; e += 256)
    ((uint4*)beta_s)[e] = ((const uint4*)beta_bf)[e];
  // sd stage: 1200 float4 tasks; task -> (k = task/12, c4 = task%12)
  for (int task = t; task < 1200; task += 256) {
    const int k = task / 12, c4 = task % 12;
    const float4 v = *(const float4*)&sd[(size_t)k * (3 * NV) + col0 + c4 * 4];
    *(float4*)&sdf[k * 48 + c4 * 4] = v;
  }
  for (int e = t; e < 512; e += 256) {
    const int n = e >> 5, k = e & 31;
    float val = (k < NJ) ? w[(n0v + n) * NJ + k] : (k == NJ ? 1.0f : 0.0f);
    wT_s[n * 40 + k] = rne_bf16(val);
  }
  if (t < 48) vt_s[t] = vt[col0 + t];
  __syncthreads();

  // phase 1: D(64x48) = beta(64x128) @ sd(128x48); wave = M-tile of 16 batches
  bf16x8 af[4];
#pragma unroll
  for (int ks = 0; ks < 4; ++ks)
    af[ks] = *(const bf16x8*)&beta_s[(wv * 16 + l15) * 136 + ks * 32 + q * 8];
  f32x4 acc[3];
#pragma unroll
  for (int nt = 0; nt < 3; ++nt) acc[nt] = (f32x4){0.f, 0.f, 0.f, 0.f};
#pragma unroll
  for (int ks = 0; ks < 4; ++ks) {
#pragma unroll
    for (int nt = 0; nt < 3; ++nt) {
      bf16x8 bfr;
#pragma unroll
      for (int jj = 0; jj < 8; ++jj) {
        const int kk = ks * 32 + q * 8 + jj;       // ks<3 => kk<96<P always
        if (ks == 3) {
          const int ka = (kk < P) ? kk : 0;        // safe addr
          float f = sdf[ka * 48 + nt * 16 + l15];
          bfr[jj] = (short)((kk < P) ? rne_bf16(f) : (unsigned short)0);
        } else {
          bfr[jj] = (short)rne_bf16(sdf[kk * 48 + nt * 16 + l15]);
        }
      }
      acc[nt] = __builtin_amdgcn_mfma_f32_16x16x32_bf16(af[ks], bfr, acc[nt], 0, 0, 0);
    }
  }
  float vtv[3];
#pragma unroll
  for (int nt = 0; nt < 3; ++nt) vtv[nt] = vt_s[nt * 16 + l15];
  __syncthreads();   // beta_s fragment reads done before aliased vhf writes

#pragma unroll
  for (int nt = 0; nt < 3; ++nt) {
    const int n = nt * 16 + l15;
    const int v = n / 3, c = n - 3 * v;
#pragma unroll
    for (int r = 0; r < 4; ++r) {
      const int m = wv * 16 + q * 4 + r;   // batch
      vhf[m * 68 + v * 4 + c] = acc[nt][r] + vtv[nt];
    }
  }
  __syncthreads();

  // phase 2: T = G1A(b) @ w^T via MFMA; dot with vh; store direct.
  const bf16x8 wf = *(const bf16x8*)&wT_s[l15 * 40 + q * 8];
  const f32x4 zero = (f32x4){0.f, 0.f, 0.f, 0.f};
#pragma unroll 4
  for (int bi = 0; bi < 16; ++bi) {
    const int b = wv * 16 + bi;
    const bf16x8 gf = *(const bf16x8*)&G1A[(size_t)b * 512 + l15 * 32 + q * 8];
    const f32x4 d = __builtin_amdgcn_mfma_f32_16x16x32_bf16(gf, wf, zero, 0, 0, 0);
    const float4 vh = *(const float4*)&vhf[b * 68 + l15 * 4];
    if (q < 3) {
      out[(size_t)b * (NV * 3) + col0 + l15 * 3 + q] =
          d[0] * vh.x + d[1] * vh.y + d[2] * vh.z + d[3];
    }
  }
}

// ---------------------------------------------------------------------------
// Kernel 3: skeleton keypoints (R0 version, 1920 blocks — full parallelism).
// ---------------------------------------------------------------------------
__global__ void k_skel(const float* __restrict__ posed,
                       const int*   __restrict__ joint_idx,
                       const int*   __restrict__ add_idx,
                       float*       __restrict__ skel) {
  const int j = blockIdx.x;   // 0..29
  const int b = blockIdx.y;   // 0..63
  const int t = threadIdx.x;  // 0..127
  const int idx = (j < 23) ? joint_idx[j * KG + t] : add_idx[(j - 23) * KG + t];

  const float* p = posed + (size_t)b * NV * 3 + (size_t)idx * 3;
  float mn[3], mx[3];
#pragma unroll
  for (int c = 0; c < 3; ++c) { mn[c] = p[c]; mx[c] = p[c]; }
#pragma unroll
  for (int off = 32; off > 0; off >>= 1) {
#pragma unroll
    for (int c = 0; c < 3; ++c) {
      mn[c] = fminf(mn[c], __shfl_down(mn[c], off));
      mx[c] = fmaxf(mx[c], __shfl_down(mx[c], off));
    }
  }
  __shared__ float s_mn[2][3], s_mx[2][3];
  const int wave = t >> 6, lane = t & 63;
  if (lane == 0) {
#pragma unroll
    for (int c = 0; c < 3; ++c) { s_mn[wave][c] = mn[c]; s_mx[wave][c] = mx[c]; }
  }
  __syncthreads();
  if (t == 0) {
#pragma unroll
    for (int c = 0; c < 3; ++c) {
      float lo = fminf(s_mn[0][c], s_mn[1][c]);
      float hi = fmaxf(s_mx[0][c], s_mx[1][c]);
      skel[(b * NSK + 1 + j) * 3 + c] = 0.5f * (lo + hi);
      if (j == 0) skel[(b * NSK + 0) * 3 + c] = 0.0f;
    }
  }
}

// ---------------------------------------------------------------------------
extern "C" void kernel_launch(void* const* d_in, const int* in_sizes, int n_in,
                              void* d_out, int out_size, void* d_ws, size_t ws_size,
                              hipStream_t stream) {
  const float* beta     = (const float*)d_in[0];
  const float* pose     = (const float*)d_in[1];
  const float* trans    = (const float*)d_in[2];
  const float* sd       = (const float*)d_in[3];
  const float* vt       = (const float*)d_in[4];
  const float* w        = (const float*)d_in[5];
  // d_in[6] = reorder_index (identity arange -> unused)
  // d_in[7] = parent (implicit (i-1)/2 binary tree -> folded into k_jc)
  const int* joint_idx  = (const int*)d_in[8];
  const int* add_idx    = (const int*)d_in[9];

  float* out  = (float*)d_out;
  float* skel = out + (size_t)B * NV * 3;
  unsigned short* G1A     = (unsigned short*)d_ws;            // 64*512 us
  unsigned short* beta_bf = G1A + B * 512;                    // 64*136 us
  float* pmn = (float*)(beta_bf + B * 136);                   // 23*8*64*3 f
  float* pmx = pmn + 23 * NSUB * B * 3;
  int*   cnt = (int*)(pmx + 23 * NSUB * B * 3);

  hipMemsetAsync(cnt, 0, 16, stream);
  k_jc<<<dim3(23, NSUB), 256, 0, stream>>>(beta, sd, vt, joint_idx, pose, trans,
                                           pmn, pmx, G1A, beta_bf, cnt);
  k_skin<<<NV / TVS, 256, 0, stream>>>(sd, vt, w, beta_bf, G1A, out);
  k_skel<<<dim3(30, B), 128, 0, stream>>>(out, joint_idx, add_idx, skel);
}

// Round 5
// 178.626 us; speedup vs baseline: 1.3883x; 1.1013x over previous
//
#include <hip/hip_runtime.h>
#include <math.h>

#define B    64
#define NV   40000
#define P    100
#define KG   128
#define NJ   24
#define TVJ  16           // vertices per jpart sub-tile
#define TVS  32           // vertices per skin block
#define NSK  31           // skeleton joints: 1 zero + 23 + 7
#define NSUB (KG / TVJ)   // 8 sub-tiles per joint
#define NJS  (23 * NSUB)  // 184 jpart tiles
#define GATHER_BLK 552    // 552*256 == 184*768 gather tasks exactly

typedef __attribute__((ext_vector_type(8))) short bf16x8;
typedef __attribute__((ext_vector_type(4))) float f32x4;

__device__ __forceinline__ unsigned short rne_bf16(float f) {
  unsigned u = __float_as_uint(f);
  u = (u + 0x7FFFu + ((u >> 16) & 1u)) >> 16;
  return (unsigned short)u;
}

// ---------------------------------------------------------------------------
// Kernel 0: high-parallelism gather. The sd-column gather was k_jc's whole
// 52us (18.9MB line-granular fetch at 380 GB/s: 184 blocks can't hide
// latency). Here: 141312 one-task threads across 552 blocks keep thousands
// of loads in flight. Task -> 8 scattered loads, pack bf16x8, one uint4
// store to sdg[js][48][128]. Blocks 552..555: zero G1A + convert beta_bf
// (moved off k_jc's serial chain tail).
// ---------------------------------------------------------------------------
__global__ __launch_bounds__(256)
void k_gather(const float* __restrict__ sd,
              const float* __restrict__ beta,
              const int*   __restrict__ joint_idx,
              unsigned short* __restrict__ sdg,
              unsigned short* __restrict__ G1A,
              unsigned short* __restrict__ beta_bf) {
  if (blockIdx.x < GATHER_BLK) {
    const int tid = blockIdx.x * 256 + threadIdx.x;   // 0..141311
    const int js = tid / 768, rem = tid % 768;
    const int n = rem % 48, kg = rem / 48;
    const int j = js >> 3, s = js & 7;
    const int vidx = joint_idx[j * KG + s * TVJ + n / 3];
    const size_t colbase = (size_t)vidx * 3 + (n % 3);
    unsigned pk[4];
#pragma unroll
    for (int h = 0; h < 4; ++h) {
      const int k0 = kg * 8 + 2 * h;
      float f0 = 0.0f, f1 = 0.0f;
      if (k0 < P)     f0 = sd[(size_t)k0 * (3 * NV) + colbase];
      if (k0 + 1 < P) f1 = sd[(size_t)(k0 + 1) * (3 * NV) + colbase];
      pk[h] = (unsigned)rne_bf16(f0) | ((unsigned)rne_bf16(f1) << 16);
    }
    *(uint4*)&sdg[(size_t)js * 6144 + n * 128 + kg * 8] =
        make_uint4(pk[0], pk[1], pk[2], pk[3]);
  } else {
    const int e0 = (blockIdx.x - GATHER_BLK) * 256 + threadIdx.x;  // 0..1023
    const uint4 z4 = make_uint4(0, 0, 0, 0);
    for (int i = e0; i < 4096; i += 1024) ((uint4*)G1A)[i] = z4;   // 64KB zero
    for (int i = e0; i < 64 * 136; i += 1024) {
      const int b = i / 136, k = i - b * 136;
      beta_bf[i] = (k < P) ? rne_bf16(beta[b * P + k]) : (unsigned short)0;
    }
  }
}

// ---------------------------------------------------------------------------
// Kernel 1: jpart GEMM (184 blocks; staging is now pure streaming from the
// L2-hot sdg/beta_bf) + chain folded into the LAST block via ticket.
// ---------------------------------------------------------------------------
__global__ __launch_bounds__(256)
void k_jc(const unsigned short* __restrict__ sdg,
          const unsigned short* __restrict__ beta_bf,
          const float* __restrict__ vt,
          const int*   __restrict__ joint_idx,
          const float* __restrict__ pose,
          const float* __restrict__ trans,
          float*       __restrict__ pmn,
          float*       __restrict__ pmx,
          unsigned short* __restrict__ G1A,
          int*         __restrict__ cnt) {
  const int j = blockIdx.x;   // 0..22
  const int s = blockIdx.y;   // 0..7
  const int js = j * NSUB + s;
  const int t = threadIdx.x;  // 0..255
  const int lane = t & 63, wv = t >> 6;
  const int l15 = lane & 15, qd = lane >> 4;

  __shared__ __align__(16) unsigned char smem[55296];
  unsigned short* beta_s = (unsigned short*)smem;            // [64][136]
  unsigned short* sdT_s  = (unsigned short*)(smem + 17408);  // [48][136]
  float*          vt_s   = (float*)(smem + 30464);           // [48]
  int*            idx_s  = (int*)(smem + 30656);             // [16]
  float*          pos_s  = (float*)smem;                     // alias [64][68]
  __shared__ int s_old;

  if (t < TVJ) idx_s[t] = joint_idx[j * KG + s * TVJ + t];
  __syncthreads();

  for (int e = t; e < 1088; e += 256)
    ((uint4*)beta_s)[e] = ((const uint4*)beta_bf)[e];
  for (int e = t; e < 768; e += 256) {
    const int n = e >> 4, kg = e & 15;
    *(uint4*)&sdT_s[n * 136 + kg * 8] =
        *(const uint4*)&sdg[(size_t)js * 6144 + (e << 3)];
  }
  if (t < 48) vt_s[t] = vt[(size_t)idx_s[t / 3] * 3 + (t % 3)];
  __syncthreads();

  // D(64x48) = beta(64x128) @ sdT(128x48); wave = M-tile of 16 batches
  bf16x8 af[4];
#pragma unroll
  for (int ks = 0; ks < 4; ++ks)
    af[ks] = *(const bf16x8*)&beta_s[(wv * 16 + l15) * 136 + ks * 32 + qd * 8];
  f32x4 acc[3];
#pragma unroll
  for (int nt = 0; nt < 3; ++nt) acc[nt] = (f32x4){0.f, 0.f, 0.f, 0.f};
#pragma unroll
  for (int ks = 0; ks < 4; ++ks) {
#pragma unroll
    for (int nt = 0; nt < 3; ++nt) {
      const bf16x8 bf = *(const bf16x8*)&sdT_s[(nt * 16 + l15) * 136 + ks * 32 + qd * 8];
      acc[nt] = __builtin_amdgcn_mfma_f32_16x16x32_bf16(af[ks], bf, acc[nt], 0, 0, 0);
    }
  }
  float vtv[3];
#pragma unroll
  for (int nt = 0; nt < 3; ++nt) vtv[nt] = vt_s[nt * 16 + l15];
  __syncthreads();

#pragma unroll
  for (int nt = 0; nt < 3; ++nt) {
    const int n = nt * 16 + l15;
    const int v = n / 3, c = n - 3 * v;
#pragma unroll
    for (int r = 0; r < 4; ++r) {
      const int m = wv * 16 + qd * 4 + r;
      pos_s[m * 68 + v * 4 + c] = acc[nt][r] + vtv[nt];
    }
  }
  __syncthreads();

  if (t < 192) {
    const int b = t / 3, c = t % 3;
    float lo = 1e30f, hi = -1e30f;
#pragma unroll
    for (int v = 0; v < TVJ; ++v) {
      const float val = pos_s[b * 68 + v * 4 + c];
      lo = fminf(lo, val); hi = fmaxf(hi, val);
    }
    pmn[(js * B + b) * 3 + c] = lo;
    pmx[(js * B + b) * 3 + c] = hi;
  }

  // ------------------- ticket: last block runs the chain -------------------
  __syncthreads();
  if (t == 0) { __threadfence(); s_old = atomicAdd(cnt, 1); }  // release
  __syncthreads();
  if (s_old != NJS - 1) return;
  __threadfence();                    // acquire

  float* Jl_c = (float*)smem;             // [(j*3+c)*64 + b]  18432 B
  float* Gl   = (float*)(smem + 18432);   // [b][12][12]       36864 B

  for (int e = t; e < 192; e += 256) Jl_c[e] = 0.0f;
  for (int e = t; e < 23 * 192; e += 256) {
    const int jj = e / 192, rem = e - jj * 192;
    float lo = 1e30f, hi = -1e30f;
#pragma unroll
    for (int s2 = 0; s2 < NSUB; ++s2) {
      lo = fminf(lo, pmn[(jj * NSUB + s2) * 192 + rem]);
      hi = fmaxf(hi, pmx[(jj * NSUB + s2) * 192 + rem]);
    }
    const int b = rem / 3, c = rem - b * 3;
    Jl_c[((jj + 1) * 3 + c) * 64 + b] = 0.5f * (lo + hi);
  }
  __syncthreads();

  if (t < 64) {
    const int b = t;
    float px = pose[b * 72 + 0], py = pose[b * 72 + 1], pz = pose[b * 72 + 2];
    float G_[12];
#pragma unroll 1
    for (int i = 0; i < NJ; ++i) {
      float nx = 0.f, ny = 0.f, nz = 0.f;
      if (i < NJ - 1) {
        nx = pose[b * 72 + (i + 1) * 3 + 0];
        ny = pose[b * 72 + (i + 1) * 3 + 1];
        nz = pose[b * 72 + (i + 1) * 3 + 2];
      }
      const float th = fmaxf(sqrtf(px * px + py * py + pz * pz), 1e-6f);
      const float xh = px / th, yh = py / th, zh = pz / th;
      const float cc = cosf(th), ss = sinf(th), oo = 1.0f - cc;
      float R9[9];
      R9[0] = cc + oo * xh * xh;      R9[1] = oo * xh * yh - ss * zh; R9[2] = oo * xh * zh + ss * yh;
      R9[3] = oo * xh * yh + ss * zh; R9[4] = cc + oo * yh * yh;      R9[5] = oo * yh * zh - ss * xh;
      R9[6] = oo * xh * zh - ss * yh; R9[7] = oo * yh * zh + ss * xh; R9[8] = cc + oo * zh * zh;

      const float ji0 = Jl_c[(i * 3 + 0) * 64 + b];
      const float ji1 = Jl_c[(i * 3 + 1) * 64 + b];
      const float ji2 = Jl_c[(i * 3 + 2) * 64 + b];

      if (i == 0) {
#pragma unroll
        for (int r = 0; r < 3; ++r) {
          G_[r * 4 + 0] = R9[r * 3 + 0];
          G_[r * 4 + 1] = R9[r * 3 + 1];
          G_[r * 4 + 2] = R9[r * 3 + 2];
          G_[r * 4 + 3] = 0.0f;
        }
      } else {
        const int p = (i - 1) >> 1;
        const float d0 = ji0 - Jl_c[(p * 3 + 0) * 64 + b];
        const float d1 = ji1 - Jl_c[(p * 3 + 1) * 64 + b];
        const float d2 = ji2 - Jl_c[(p * 3 + 2) * 64 + b];
        float Gn[12];
#pragma unroll
        for (int r = 0; r < 3; ++r) {
          const float g0 = Gl[(b * 12 + p) * 12 + r * 4 + 0];
          const float g1 = Gl[(b * 12 + p) * 12 + r * 4 + 1];
          const float g2 = Gl[(b * 12 + p) * 12 + r * 4 + 2];
          const float g3 = Gl[(b * 12 + p) * 12 + r * 4 + 3];
          Gn[r * 4 + 0] = g0 * R9[0] + g1 * R9[3] + g2 * R9[6];
          Gn[r * 4 + 1] = g0 * R9[1] + g1 * R9[4] + g2 * R9[7];
          Gn[r * 4 + 2] = g0 * R9[2] + g1 * R9[5] + g2 * R9[8];
          Gn[r * 4 + 3] = g0 * d0 + g1 * d1 + g2 * d2 + g3;
        }
#pragma unroll
        for (int e = 0; e < 12; ++e) G_[e] = Gn[e];
      }
      if (i < 12) {
#pragma unroll
        for (int e = 0; e < 12; ++e) Gl[(b * 12 + i) * 12 + e] = G_[e];
      }
#pragma unroll
      for (int r = 0; r < 3; ++r) {
        const float tc = G_[r * 4 + 0] * ji0 + G_[r * 4 + 1] * ji1 + G_[r * 4 + 2] * ji2;
        G1A[b * 512 + (r * 4 + 0) * 32 + i] = rne_bf16(G_[r * 4 + 0]);
        G1A[b * 512 + (r * 4 + 1) * 32 + i] = rne_bf16(G_[r * 4 + 1]);
        G1A[b * 512 + (r * 4 + 2) * 32 + i] = rne_bf16(G_[r * 4 + 2]);
        G1A[b * 512 + (r * 4 + 3) * 32 + i] = rne_bf16(G_[r * 4 + 3] - tc);
      }
      px = nx; py = ny; pz = nz;
    }
  } else if (t >= 192) {
#pragma unroll
    for (int k = 0; k < 3; ++k) {
      const int e = (t - 192) * 3 + k;
      const int b = e / 3, r = e - b * 3;
      G1A[b * 512 + (r * 4 + 3) * 32 + 24] = rne_bf16(trans[b * 3 + r]);
    }
  }
}

// ---------------------------------------------------------------------------
// Kernel 2: fused shape-blend GEMM + skinning — R1 body verbatim (bf16 LDS
// staging, TVS=32, direct global stores). The R4 f32-tile/on-the-fly-convert
// variant was a ~2x regression (fragment-build VALU + conflicted ds_read).
// ---------------------------------------------------------------------------
__global__ __launch_bounds__(256)
void k_skin(const float* __restrict__ sd,
            const float* __restrict__ vt,
            const float* __restrict__ w,
            const unsigned short* __restrict__ beta_bf,
            const unsigned short* __restrict__ G1A,
            float*       __restrict__ out) {
  const int n0v  = blockIdx.x * TVS;
  const int col0 = n0v * 3;            // 96 columns per block
  const int t  = threadIdx.x;
  const int lane = t & 63, wv = t >> 6;
  const int l15 = lane & 15, q = lane >> 4;

  __shared__ __align__(16) unsigned char smem[46464];
  unsigned short* beta_s = (unsigned short*)smem;             // [64][136]  17408 B
  unsigned short* sdT_s  = (unsigned short*)(smem + 17408);   // [96][136]  26112 B
  unsigned short* wT_s   = (unsigned short*)(smem + 43520);   // [32][40]    2560 B
  float*          vt_s   = (float*)(smem + 46080);            // [96]         384 B
  float*          vhf    = (float*)smem;                      // alias [64][128] f32

  for (int e = t; e < 1088; e += 256)
    ((uint4*)beta_s)[e] = ((const uint4*)beta_bf)[e];
  for (int task = t; task < 1536; task += 256) {
    const int n = task % 96, kg = task / 96;
    unsigned pk[4];
#pragma unroll
    for (int h = 0; h < 4; ++h) {
      const int k0 = kg * 8 + 2 * h;
      float f0 = 0.0f, f1 = 0.0f;
      if (k0 < P)     f0 = sd[(size_t)k0 * (3 * NV) + col0 + n];
      if (k0 + 1 < P) f1 = sd[(size_t)(k0 + 1) * (3 * NV) + col0 + n];
      pk[h] = (unsigned)rne_bf16(f0) | ((unsigned)rne_bf16(f1) << 16);
    }
    *(uint4*)&sdT_s[n * 136 + kg * 8] = make_uint4(pk[0], pk[1], pk[2], pk[3]);
  }
  for (int e = t; e < 1024; e += 256) {
    const int n = e >> 5, k = e & 31;
    float val = (k < NJ) ? w[(n0v + n) * NJ + k] : (k == NJ ? 1.0f : 0.0f);
    wT_s[n * 40 + k] = rne_bf16(val);
  }
  if (t < 96) vt_s[t] = vt[col0 + t];
  __syncthreads();

  // phase 1: D(64x96) = beta(64x128) @ sdT(128x96)
  bf16x8 af[4];
#pragma unroll
  for (int ks = 0; ks < 4; ++ks)
    af[ks] = *(const bf16x8*)&beta_s[(wv * 16 + l15) * 136 + ks * 32 + q * 8];
  f32x4 acc[6];
#pragma unroll
  for (int nt = 0; nt < 6; ++nt) acc[nt] = (f32x4){0.f, 0.f, 0.f, 0.f};
#pragma unroll
  for (int ks = 0; ks < 4; ++ks) {
#pragma unroll
    for (int nt = 0; nt < 6; ++nt) {
      const bf16x8 bf = *(const bf16x8*)&sdT_s[(nt * 16 + l15) * 136 + ks * 32 + q * 8];
      acc[nt] = __builtin_amdgcn_mfma_f32_16x16x32_bf16(af[ks], bf, acc[nt], 0, 0, 0);
    }
  }
  __syncthreads();   // fragment reads done before aliased writes

#pragma unroll
  for (int nt = 0; nt < 6; ++nt) {
    const int n = nt * 16 + l15;
    const int v = n / 3, c = n - 3 * v;
    const float vtn = vt_s[n];
#pragma unroll
    for (int r = 0; r < 4; ++r) {
      const int m = wv * 16 + q * 4 + r;   // batch
      vhf[m * 128 + v * 4 + c] = acc[nt][r] + vtn;
    }
  }
  __syncthreads();

  // phase 2: T = G1A(b) @ w^T via MFMA; dot with vh; store direct.
  const bf16x8 wf0 = *(const bf16x8*)&wT_s[l15 * 40 + q * 8];
  const bf16x8 wf1 = *(const bf16x8*)&wT_s[(16 + l15) * 40 + q * 8];
  const f32x4 zero = (f32x4){0.f, 0.f, 0.f, 0.f};
#pragma unroll 4
  for (int bi = 0; bi < 16; ++bi) {
    const int b = wv * 16 + bi;
    const bf16x8 gf = *(const bf16x8*)&G1A[(size_t)b * 512 + l15 * 32 + q * 8];
    const f32x4 d0 = __builtin_amdgcn_mfma_f32_16x16x32_bf16(gf, wf0, zero, 0, 0, 0);
    const f32x4 d1 = __builtin_amdgcn_mfma_f32_16x16x32_bf16(gf, wf1, zero, 0, 0, 0);
    const float4 vh0 = *(const float4*)&vhf[b * 128 + l15 * 4];
    const float4 vh1 = *(const float4*)&vhf[b * 128 + 64 + l15 * 4];
    if (q < 3) {
      out[(size_t)b * (NV * 3) + col0 + l15 * 3 + q] =
          d0[0] * vh0.x + d0[1] * vh0.y + d0[2] * vh0.z + d0[3];
      out[(size_t)b * (NV * 3) + col0 + 48 + l15 * 3 + q] =
          d1[0] * vh1.x + d1[1] * vh1.y + d1[2] * vh1.z + d1[3];
    }
  }
}

// ---------------------------------------------------------------------------
// Kernel 3: skeleton keypoints (1920 blocks — full parallelism).
// ---------------------------------------------------------------------------
__global__ void k_skel(const float* __restrict__ posed,
                       const int*   __restrict__ joint_idx,
                       const int*   __restrict__ add_idx,
                       float*       __restrict__ skel) {
  const int j = blockIdx.x;   // 0..29
  const int b = blockIdx.y;   // 0..63
  const int t = threadIdx.x;  // 0..127
  const int idx = (j < 23) ? joint_idx[j * KG + t] : add_idx[(j - 23) * KG + t];

  const float* p = posed + (size_t)b * NV * 3 + (size_t)idx * 3;
  float mn[3], mx[3];
#pragma unroll
  for (int c = 0; c < 3; ++c) { mn[c] = p[c]; mx[c] = p[c]; }
#pragma unroll
  for (int off = 32; off > 0; off >>= 1) {
#pragma unroll
    for (int c = 0; c < 3; ++c) {
      mn[c] = fminf(mn[c], __shfl_down(mn[c], off));
      mx[c] = fmaxf(mx[c], __shfl_down(mx[c], off));
    }
  }
  __shared__ float s_mn[2][3], s_mx[2][3];
  const int wave = t >> 6, lane = t & 63;
  if (lane == 0) {
#pragma unroll
    for (int c = 0; c < 3; ++c) { s_mn[wave][c] = mn[c]; s_mx[wave][c] = mx[c]; }
  }
  __syncthreads();
  if (t == 0) {
#pragma unroll
    for (int c = 0; c < 3; ++c) {
      float lo = fminf(s_mn[0][c], s_mn[1][c]);
      float hi = fmaxf(s_mx[0][c], s_mx[1][c]);
      skel[(b * NSK + 1 + j) * 3 + c] = 0.5f * (lo + hi);
      if (j == 0) skel[(b * NSK + 0) * 3 + c] = 0.0f;
    }
  }
}

// ---------------------------------------------------------------------------
extern "C" void kernel_launch(void* const* d_in, const int* in_sizes, int n_in,
                              void* d_out, int out_size, void* d_ws, size_t ws_size,
                              hipStream_t stream) {
  const float* beta     = (const float*)d_in[0];
  const float* pose     = (const float*)d_in[1];
  const float* trans    = (const float*)d_in[2];
  const float* sd       = (const float*)d_in[3];
  const float* vt       = (const float*)d_in[4];
  const float* w        = (const float*)d_in[5];
  // d_in[6] = reorder_index (identity arange -> unused)
  // d_in[7] = parent (implicit (i-1)/2 binary tree -> folded into k_jc)
  const int* joint_idx  = (const int*)d_in[8];
  const int* add_idx    = (const int*)d_in[9];

  float* out  = (float*)d_out;
  float* skel = out + (size_t)B * NV * 3;
  unsigned short* G1A     = (unsigned short*)d_ws;            // 65536 B
  unsigned short* beta_bf = G1A + B * 512;                    // 17408 B
  float* pmn = (float*)(beta_bf + B * 136);                   // 141312 B
  float* pmx = pmn + NJS * B * 3;                             // 141312 B
  int*   cnt = (int*)(pmx + NJS * B * 3);                     // 16 B
  unsigned short* sdg = (unsigned short*)(cnt + 4);           // 184*6144*2 B

  hipMemsetAsync(cnt, 0, 16, stream);
  k_gather<<<GATHER_BLK + 4, 256, 0, stream>>>(sd, beta, joint_idx,
                                               sdg, G1A, beta_bf);
  k_jc<<<dim3(23, NSUB), 256, 0, stream>>>(sdg, beta_bf, vt, joint_idx,
                                           pose, trans, pmn, pmx, G1A, cnt);
  k_skin<<<NV / TVS, 256, 0, stream>>>(sd, vt, w, beta_bf, G1A, out);
  k_skel<<<dim3(30, B), 128, 0, stream>>>(out, joint_idx, add_idx, skel);
}